// Round 2
// baseline (1046.136 us; speedup 1.0000x reference)
//
#include <hip/hip_runtime.h>
#include <stdint.h>

#define NB   256      // batch
#define NS   196      // seq len (= hidden seq)
#define NF   384      // in/out features
#define NH   8        // heads
#define NEH  48       // per-head dim
#define NIT  10
#define SP   224      // padded seq (multiple of 32, 14 tiles of 16)
#define EP   64       // padded per-head dim (K padding; N uses exactly 48)
#define NBH  2048     // NB*NH
#define NBS  50176    // NB*NS

using f32x4  = __attribute__((ext_vector_type(4))) float;
using u16x8  = __attribute__((ext_vector_type(8))) uint16_t;
using u16x4  = __attribute__((ext_vector_type(4))) uint16_t;
using bf16x8 = __attribute__((ext_vector_type(8))) __bf16;

static __device__ __forceinline__ float bf2f(uint16_t u){
  union { uint32_t u32; float f; } c; c.u32 = (uint32_t)u << 16; return c.f;
}
static __device__ __forceinline__ uint16_t f2bf(float f){
  union { float f; uint32_t u32; } c; c.f = f;
  return (uint16_t)((c.u32 + 0x7fffu + ((c.u32 >> 16) & 1u)) >> 16);
}
static __device__ __forceinline__ bf16x8 ld8(const uint16_t* p){
  return __builtin_bit_cast(bf16x8, *(const u16x8*)p);
}
#define MFMA16(a,b,c) __builtin_amdgcn_mfma_f32_16x16x32_bf16((a),(b),(c),0,0,0)

// ---------------- prep kernels ----------------

// global_weight [8][196][196] -> gw_b [8][224][224] (o,i) and gwt_b [8][224][224] (i,o), bf16, zero-padded
__global__ void k_prep_gw(const float* __restrict__ gw, uint16_t* __restrict__ gw_b,
                          uint16_t* __restrict__ gwt_b){
  int idx = blockIdx.x * 256 + threadIdx.x;
  if (idx >= NH*SP*SP) return;
  int h = idx / (SP*SP);
  int r = (idx / SP) % SP;   // o
  int c = idx % SP;          // i
  float v = (r < NS && c < NS) ? gw[((size_t)h*NS + r)*NS + c] : 0.f;
  uint16_t bv = f2bf(v);
  gw_b[idx] = bv;
  gwt_b[((size_t)h*SP + c)*SP + r] = bv;
}

// local_weight pad/transpose + embed_w/out_w fp32->bf16 (same layout)
__global__ void k_prep_small(const float* __restrict__ lw, const float* __restrict__ ew,
                             const float* __restrict__ ow,
                             uint16_t* __restrict__ lw_b, uint16_t* __restrict__ lwt_b,
                             uint16_t* __restrict__ ew_b, uint16_t* __restrict__ ow_b){
  int idx = blockIdx.x * 256 + threadIdx.x;
  if (idx < EP*EP){
    int f = idx >> 6, e = idx & 63;
    float v = (f < NEH && e < NEH) ? lw[f*NEH + e] : 0.f;
    uint16_t bv = f2bf(v);
    lw_b[f*EP + e] = bv;     // [f][e]
    lwt_b[e*EP + f] = bv;    // [e][f]
  }
  if (idx < NF*NF){
    ew_b[idx] = f2bf(ew[idx]);
    ow_b[idx] = f2bf(ow[idx]);
  }
}

// h0 [B,196,8,48] -> L1-normalized h_b [2048][224][64] bf16, zero-padded
__global__ void k_prep_h(const float* __restrict__ h0, uint16_t* __restrict__ h_b){
  int idx = blockIdx.x * 256 + threadIdx.x;
  if (idx >= NBH*SP) return;
  int bh = idx / SP, o = idx % SP;
  int b = bh >> 3, h = bh & 7;
  uint16_t* dst = h_b + (size_t)idx * EP;
  if (o < NS){
    const float* src = h0 + (((size_t)(b*NS + o))*NH + h)*NEH;
    float s = 0.f;
    float v[48];
    #pragma unroll
    for (int j = 0; j < NEH; ++j){ v[j] = src[j]; s += fabsf(v[j]); }
    s = fmaxf(s, 1e-12f);
    float inv = 1.f / s;
    #pragma unroll
    for (int j = 0; j < NEH; ++j) dst[j] = f2bf(v[j] * inv);
    #pragma unroll
    for (int j = NEH; j < EP; ++j) dst[j] = 0;
  } else {
    #pragma unroll
    for (int j = 0; j < EP; ++j) dst[j] = 0;
  }
}

// ---------------- embed GEMM + input prep ----------------
// xe = clamp(x @ embed_w^T + b, 1e-6); inp = xe / rowsum48 -> inp_ws [2048][196][64] bf16
__global__ __launch_bounds__(256) void k_embed(const float* __restrict__ x,
    const uint16_t* __restrict__ ew_b, const float* __restrict__ eb,
    uint16_t* __restrict__ inp_ws){
  const int wave = threadIdx.x >> 6, lane = threadIdx.x & 63;
  const int lg = lane >> 4, li = lane & 15;
  const int m0 = blockIdx.x * 64 + wave * 16;     // this wave's 16 rows
  f32x4 acc[24];
  #pragma unroll
  for (int i = 0; i < 24; ++i) acc[i] = (f32x4)0.0f;
  const float* ap = x + (size_t)(m0 + li) * NF + 8*lg;
  for (int kt = 0; kt < 12; ++kt){
    f32x4 a0 = *(const f32x4*)(ap + kt*32);
    f32x4 a1 = *(const f32x4*)(ap + kt*32 + 4);
    u16x8 au;
    #pragma unroll
    for (int j = 0; j < 4; ++j){ au[j] = f2bf(a0[j]); au[j+4] = f2bf(a1[j]); }
    bf16x8 a = __builtin_bit_cast(bf16x8, au);
    #pragma unroll
    for (int nt = 0; nt < 24; ++nt){
      bf16x8 b = ld8(ew_b + (size_t)(nt*16 + li)*NF + kt*32 + 8*lg);
      acc[nt] = MFMA16(a, b, acc[nt]);
    }
  }
  // epilogue: +bias, clamp, per-head L1 normalize, write bf16
  #pragma unroll
  for (int hh = 0; hh < 8; ++hh){
    float xec[3][4];
    float s[4] = {0.f, 0.f, 0.f, 0.f};
    #pragma unroll
    for (int j = 0; j < 3; ++j){
      int nt = hh*3 + j;
      float bias = eb[nt*16 + li];
      #pragma unroll
      for (int r = 0; r < 4; ++r){
        float v = fmaxf(acc[nt][r] + bias, 1e-6f);
        xec[j][r] = v; s[r] += v;
      }
    }
    #pragma unroll
    for (int r = 0; r < 4; ++r){
      float t = s[r];
      t += __shfl_xor(t, 1); t += __shfl_xor(t, 2);
      t += __shfl_xor(t, 4); t += __shfl_xor(t, 8);
      s[r] = t;
    }
    #pragma unroll
    for (int r = 0; r < 4; ++r){
      int m = m0 + 4*lg + r;
      int b = m / NS, si = m - b*NS;
      float inv = 1.f / s[r];
      #pragma unroll
      for (int j = 0; j < 3; ++j){
        inp_ws[((size_t)(b*NH + hh)*NS + si)*EP + j*16 + li] = f2bf(xec[j][r] * inv);
      }
    }
  }
}

// ---------------- main NNMF fixed-point kernel ----------------
// One block per (b,h). 8 waves. All 10 iterations fused; h held fp32 in registers.
// LDS: hT [64][232] bf16 (h transposed, [f][o]); buf1 [224][72] bf16 (t1/rec/ratio),
//      aliased as t2T [48][232] after step4.
__global__ __launch_bounds__(512) void k_main(
    const uint16_t* __restrict__ gw_b,   // [H][SP][SP] (o,i)
    const uint16_t* __restrict__ gwt_b,  // [H][SP][SP] (i,o)
    const uint16_t* __restrict__ lw_b,   // [EP][EP] (f,e)
    const uint16_t* __restrict__ lwt_b,  // [EP][EP] (e,f)
    const uint16_t* __restrict__ inp_ws, // [BH][NS][EP]
    uint16_t* __restrict__ h_b)          // [BH][SP][EP]
{
  __shared__ __align__(16) uint16_t buf1[SP][72];
  __shared__ __align__(16) uint16_t hT[EP][232];

  const int bh = blockIdx.x;
  const int hh = bh & 7;
  const int tid = threadIdx.x;
  const int wave = tid >> 6;
  const int lane = tid & 63;
  const int lg = lane >> 4;
  const int li = lane & 15;

  { // zero LDS (pad invariants rely on this)
    uint32_t* p1 = (uint32_t*)&buf1[0][0];
    for (int i = tid; i < SP*72/2; i += 512) p1[i] = 0u;
    uint32_t* p2 = (uint32_t*)&hT[0][0];
    for (int i = tid; i < EP*232/2; i += 512) p2[i] = 0u;
  }
  __syncthreads();

  uint16_t* __restrict__ hrow = h_b + (size_t)bh * SP * EP;
  for (int idx = tid; idx < SP*8; idx += 512){  // h -> hT (transpose load)
    int o = idx >> 3, f8 = (idx & 7) << 3;
    u16x8 v = *(const u16x8*)(hrow + (size_t)o*EP + f8);
    #pragma unroll
    for (int j = 0; j < 8; ++j) hT[f8+j][o] = v[j];
  }
  __syncthreads();

  // fp32 h state in registers: tile mt=wave (hr0) and mt=wave+8 (hr1, if <13)
  float hr0[3][4], hr1[3][4];
  {
    int ob = wave*16 + 4*lg;
    #pragma unroll
    for (int nt = 0; nt < 3; ++nt){
      u16x4 hv = *(const u16x4*)&hT[nt*16 + li][ob];
      #pragma unroll
      for (int r = 0; r < 4; ++r) hr0[nt][r] = bf2f(hv[r]);
    }
  }
  if (wave + 8 < 13){
    int ob = (wave+8)*16 + 4*lg;
    #pragma unroll
    for (int nt = 0; nt < 3; ++nt){
      u16x4 hv = *(const u16x4*)&hT[nt*16 + li][ob];
      #pragma unroll
      for (int r = 0; r < 4; ++r) hr1[nt][r] = bf2f(hv[r]);
    }
  } else {
    #pragma unroll
    for (int nt = 0; nt < 3; ++nt)
      #pragma unroll
      for (int r = 0; r < 4; ++r) hr1[nt][r] = 0.f;
  }

  // preload local-weight B-fragments (constant across iterations)
  bf16x8 lwtF[3][2], lwF[3][2];
  #pragma unroll
  for (int nt = 0; nt < 3; ++nt)
    #pragma unroll
    for (int kt = 0; kt < 2; ++kt){
      lwtF[nt][kt] = ld8(lwt_b + (size_t)(nt*16 + li)*EP + kt*32 + 8*lg); // rec: B[k=f][n=e]
      lwF [nt][kt] = ld8(lw_b  + (size_t)(nt*16 + li)*EP + kt*32 + 8*lg); // fwd: B[k=e][n=f]
    }

  const uint16_t* __restrict__ gwh  = gw_b  + (size_t)hh * SP * SP;
  const uint16_t* __restrict__ gwth = gwt_b + (size_t)hh * SP * SP;
  uint16_t* const t2T = &buf1[0][0];   // aliased [48][232] view

  auto gemm_lw = [&](int mt, const bf16x8 (&bf)[3][2], f32x4 (&acc)[3]){
    #pragma unroll
    for (int i = 0; i < 3; ++i) acc[i] = (f32x4)0.0f;
    #pragma unroll
    for (int kt = 0; kt < 2; ++kt){
      bf16x8 a = ld8(&buf1[mt*16 + li][kt*32 + 8*lg]);
      #pragma unroll
      for (int nt = 0; nt < 3; ++nt) acc[nt] = MFMA16(a, bf[nt][kt], acc[nt]);
    }
  };
  auto store_rows = [&](int mt, const f32x4 (&acc)[3]){
    #pragma unroll
    for (int nt = 0; nt < 3; ++nt)
      #pragma unroll
      for (int r = 0; r < 4; ++r)
        buf1[mt*16 + 4*lg + r][nt*16 + li] = f2bf(acc[nt][r]);
  };
  auto store_t2T = [&](int mt, const f32x4 (&acc)[3]){
    #pragma unroll
    for (int nt = 0; nt < 3; ++nt){
      u16x4 w;
      #pragma unroll
      for (int r = 0; r < 4; ++r) w[r] = f2bf(acc[nt][r]);
      *(u16x4*)(t2T + (size_t)(nt*16 + li)*232 + mt*16 + 4*lg) = w;
    }
  };
  auto step5_tile = [&](int mt, float (&hr)[3][4]){
    f32x4 acc[3];
    #pragma unroll
    for (int i = 0; i < 3; ++i) acc[i] = (f32x4)0.0f;
    const uint16_t* ab = gwh + (size_t)(mt*16 + li)*SP + 8*lg;
    #pragma unroll
    for (int kt = 0; kt < 7; ++kt){
      bf16x8 a = ld8(ab + kt*32);
      #pragma unroll
      for (int nt = 0; nt < 3; ++nt){
        bf16x8 b = ld8(t2T + (size_t)(nt*16 + li)*232 + kt*32 + 8*lg);
        acc[nt] = MFMA16(a, b, acc[nt]);
      }
    }
    int ob = mt*16 + 4*lg;
    // h = h*hu, clip; PER-ROW sums: row = ob + r, one sum per r, reduced over the 16 li lanes
    float s[4] = {0.f, 0.f, 0.f, 0.f};
    #pragma unroll
    for (int nt = 0; nt < 3; ++nt)
      #pragma unroll
      for (int r = 0; r < 4; ++r){
        float v = fmaxf(hr[nt][r] * acc[nt][r], 1e-6f);
        hr[nt][r] = v; s[r] += v;
      }
    #pragma unroll
    for (int r = 0; r < 4; ++r){
      float t = s[r];
      t += __shfl_xor(t, 1); t += __shfl_xor(t, 2);
      t += __shfl_xor(t, 4); t += __shfl_xor(t, 8);
      s[r] = t;
    }
    #pragma unroll
    for (int nt = 0; nt < 3; ++nt){
      u16x4 w;
      #pragma unroll
      for (int r = 0; r < 4; ++r){
        hr[nt][r] *= 1.f / s[r];
        w[r] = f2bf(hr[nt][r]);
      }
      if (ob < NS) *(u16x4*)&hT[nt*16 + li][ob] = w;
    }
  };

  for (int it = 0; it < NIT; ++it){
    // ---- step1: t1[i][f] = sum_o gwt[i][o]*h[o][f]  (A from global, B=hT)
    for (int mt = wave; mt < 13; mt += 8){
      f32x4 acc[3];
      #pragma unroll
      for (int i = 0; i < 3; ++i) acc[i] = (f32x4)0.0f;
      const uint16_t* ab = gwth + (size_t)(mt*16 + li)*SP + 8*lg;
      #pragma unroll
      for (int kt = 0; kt < 7; ++kt){
        bf16x8 a = ld8(ab + kt*32);
        #pragma unroll
        for (int nt = 0; nt < 3; ++nt)
          acc[nt] = MFMA16(a, ld8(&hT[nt*16 + li][kt*32 + 8*lg]), acc[nt]);
      }
      #pragma unroll
      for (int nt = 0; nt < 3; ++nt)
        #pragma unroll
        for (int r = 0; r < 4; ++r)
          buf1[mt*16 + 4*lg + r][nt*16 + li] = f2bf(acc[nt][r]);
      #pragma unroll
      for (int r = 0; r < 4; ++r)
        buf1[mt*16 + 4*lg + r][48 + li] = 0;  // re-zero K-pad cols (t2T alias dirtied them)
    }
    __syncthreads();

    // ---- step2: rec[i][e] = sum_f t1[i][f]*lw[f][e]
    f32x4 r2a[3], r2b[3];
    gemm_lw(wave, lwtF, r2a);
    if (wave + 8 < 13) gemm_lw(wave + 8, lwtF, r2b);
    __syncthreads();
    store_rows(wave, r2a);
    if (wave + 8 < 13) store_rows(wave + 8, r2b);
    __syncthreads();

    // ---- ratio[i][e] = inp[i][e] * sum_e(clip(rec)) / clip(rec[i][e]), in place, rows<196
    if (tid < NS){
      uint16_t* row = &buf1[tid][0];
      const uint16_t* inr = inp_ws + ((size_t)bh*NS + tid)*EP;
      float rv[48]; float s = 0.f;
      #pragma unroll
      for (int g = 0; g < 6; ++g){
        u16x8 v = *(const u16x8*)(row + g*8);
        #pragma unroll
        for (int j = 0; j < 8; ++j){
          float f = fmaxf(bf2f(v[j]), 1e-6f);
          rv[g*8+j] = f; s += f;
        }
      }
      #pragma unroll
      for (int g = 0; g < 6; ++g){
        u16x8 iv = *(const u16x8*)(inr + g*8);
        u16x8 w;
        #pragma unroll
        for (int j = 0; j < 8; ++j)
          w[j] = f2bf(bf2f(iv[j]) * s / rv[g*8+j]);
        *(u16x8*)(row + g*8) = w;
      }
    }
    __syncthreads();

    // ---- step4: t2[i][f] = sum_e ratio[i][e]*lw[f][e]; 14 m-tiles (tile13 writes the zero i-pad)
    f32x4 r4a[3], r4b[3];
    gemm_lw(wave, lwF, r4a);
    if (wave + 8 < 14) gemm_lw(wave + 8, lwF, r4b);
    __syncthreads();
    store_t2T(wave, r4a);
    if (wave + 8 < 14) store_t2T(wave + 8, r4b);
    __syncthreads();

    // ---- step5: hu[o][f] = sum_i gw[o][i]*t2[i][f]; h = norm(clip(h*hu))
    step5_tile(wave, hr0);
    if (wave + 8 < 13) step5_tile(wave + 8, hr1);
    __syncthreads();
  }

  // write back h (rows <196; pad rows in h_b already zeroed by prep)
  for (int idx = tid; idx < NS*8; idx += 512){
    int o = idx >> 3, f8 = (idx & 7) << 3;
    u16x8 v;
    #pragma unroll
    for (int j = 0; j < 8; ++j) v[j] = hT[f8+j][o];
    *(u16x8*)(hrow + (size_t)o*EP + f8) = v;
  }
}

// ---------------- output GEMM ----------------
// out[m][n] = sum_k h_flat[m][k]*out_w[n][k] + out_b[n]
__global__ __launch_bounds__(256) void k_out(const uint16_t* __restrict__ h_b,
    const uint16_t* __restrict__ ow_b, const float* __restrict__ obv,
    float* __restrict__ out){
  const int wave = threadIdx.x >> 6, lane = threadIdx.x & 63;
  const int lg = lane >> 4, li = lane & 15;
  const int m0 = blockIdx.x * 64 + wave * 16;
  const int m = m0 + li;
  const int b = m / NS, si = m - b*NS;
  f32x4 acc[24];
  #pragma unroll
  for (int i = 0; i < 24; ++i) acc[i] = (f32x4)0.0f;
  for (int kt = 0; kt < 12; ++kt){
    int ks = kt*32 + 8*lg;
    int hh = ks / NEH, f = ks - hh*NEH;
    bf16x8 a = ld8(h_b + ((size_t)(b*NH + hh)*SP + si)*EP + f);
    #pragma unroll
    for (int nt = 0; nt < 24; ++nt){
      bf16x8 bb = ld8(ow_b + (size_t)(nt*16 + li)*NF + kt*32 + 8*lg);
      acc[nt] = MFMA16(a, bb, acc[nt]);
    }
  }
  #pragma unroll
  for (int nt = 0; nt < 24; ++nt){
    float bias = obv[nt*16 + li];
    #pragma unroll
    for (int r = 0; r < 4; ++r)
      out[(size_t)(m0 + 4*lg + r)*NF + nt*16 + li] = acc[nt][r] + bias;
  }
}

// ---------------- launch ----------------
extern "C" void kernel_launch(void* const* d_in, const int* in_sizes, int n_in,
                              void* d_out, int out_size, void* d_ws, size_t ws_size,
                              hipStream_t stream){
  const float* x   = (const float*)d_in[0];
  const float* h0  = (const float*)d_in[1];
  const float* ew  = (const float*)d_in[2];
  const float* eb  = (const float*)d_in[3];
  const float* lw  = (const float*)d_in[4];
  const float* gw  = (const float*)d_in[5];
  const float* ow  = (const float*)d_in[6];
  const float* obv = (const float*)d_in[7];
  float* out = (float*)d_out;

  char* w = (char*)d_ws;
  size_t o_inp = 0;
  size_t o_hb  = o_inp + (size_t)NBH*NS*EP*2;
  size_t o_gw  = o_hb  + (size_t)NBH*SP*EP*2;
  size_t o_gwt = o_gw  + (size_t)NH*SP*SP*2;
  size_t o_lw  = o_gwt + (size_t)NH*SP*SP*2;
  size_t o_lwt = o_lw  + (size_t)EP*EP*2;
  size_t o_ew  = o_lwt + (size_t)EP*EP*2;
  size_t o_ow  = o_ew  + (size_t)NF*NF*2;
  size_t total = o_ow  + (size_t)NF*NF*2;
  if (ws_size < total) return;   // workspace too small -> visible failure, no corruption

  uint16_t* inp_ws = (uint16_t*)(w + o_inp);
  uint16_t* h_b    = (uint16_t*)(w + o_hb);
  uint16_t* gw_b   = (uint16_t*)(w + o_gw);
  uint16_t* gwt_b  = (uint16_t*)(w + o_gwt);
  uint16_t* lw_b   = (uint16_t*)(w + o_lw);
  uint16_t* lwt_b  = (uint16_t*)(w + o_lwt);
  uint16_t* ew_b   = (uint16_t*)(w + o_ew);
  uint16_t* ow_b   = (uint16_t*)(w + o_ow);

  k_prep_gw<<<(NH*SP*SP + 255)/256, 256, 0, stream>>>(gw, gw_b, gwt_b);
  k_prep_small<<<(NF*NF + 255)/256, 256, 0, stream>>>(lw, ew, ow, lw_b, lwt_b, ew_b, ow_b);
  k_prep_h<<<(NBH*SP + 255)/256, 256, 0, stream>>>(h0, h_b);
  k_embed<<<NBS/64, 256, 0, stream>>>(x, ew_b, eb, inp_ws);
  k_main<<<NBH, 512, 0, stream>>>(gw_b, gwt_b, lw_b, lwt_b, inp_ws, h_b);
  k_out<<<NBS/64, 256, 0, stream>>>(h_b, ow_b, obv, out);
}